// Round 10
// baseline (133.399 us; speedup 1.0000x reference)
//
#include <hip/hip_runtime.h>
#include <hip/hip_bf16.h>

typedef float  f32x4  __attribute__((ext_vector_type(4)));
typedef __bf16 bf16x8 __attribute__((ext_vector_type(8)));
typedef unsigned int   u32;
typedef unsigned short u16;
typedef u32   u32x2  __attribute__((ext_vector_type(2)));
typedef u32   u32x4  __attribute__((ext_vector_type(4)));
typedef u16   u16x4  __attribute__((ext_vector_type(4)));
typedef u16   u16x8  __attribute__((ext_vector_type(8)));

#define DEV __device__ __forceinline__

constexpr int NB = 8, T = 2048, C = 1024, H = 128;
constexpr int BT = NB * T;

union Frag {
  bf16x8 v;
  u32x4  u4;
  u32x2  u2[2];
  u32    u[4];
  u16    s[8];
};

DEV u16 f2bu(float f) {
  __hip_bfloat16 h = __float2bfloat16(f);
  return __builtin_bit_cast(u16, h);
}
DEV float bu2f(u16 u) {
  return __bfloat162float(__builtin_bit_cast(__hip_bfloat16, u));
}
DEV f32x4 MFMA(bf16x8 a, bf16x8 b, f32x4 c) {
  return __builtin_amdgcn_mfma_f32_16x16x32_bf16(a, b, c, 0, 0, 0);
}

// ---------------------------------------------------------------------------
// Lane-contiguous fragment layouts (16B/lane, 1KB/wave per load):
//   wpq/wpk: [tt8][kc32][hl2][lane64][e8]        (tile-kc stride 1024 u16)
//   wpv:     [tt8][kc32][lane64][e8]             (512)
//   qpk/kpk: [b8][tile128][hs4][hl2][lane64][e8] (tile stride 4096)
//   vpk:     [b8][kt64][ht8][lane64][e8]         (kt stride 4096)
// ---------------------------------------------------------------------------

__global__ void prep_w(const float* __restrict__ Wk, const float* __restrict__ Wq,
                       const float* __restrict__ Wv,
                       u16* __restrict__ wpq, u16* __restrict__ wpk,
                       u16* __restrict__ wpv) {
  const int id = blockIdx.x * 256 + threadIdx.x;   // 24*32*64 = 49152
  if (id >= 24 * 32 * 64) return;
  const int lane = id & 63;
  const int kc   = (id >> 6) & 31;
  const int tile = id >> 11;          // 0..23
  const int mat  = tile >> 3;         // 0=q 1=k 2=v
  const int tt   = tile & 7;
  const int n    = tt * 16 + (lane & 15);
  const float* W = (mat == 0) ? Wq : (mat == 1) ? Wk : Wv;
  u16x8 hi, lo;
  #pragma unroll
  for (int e = 0; e < 8; ++e) {
    const int k = kc * 32 + 4 * (lane >> 4) + (e & 3) + 16 * (e >> 2);
    const float w = W[(size_t)k * H + n];
    u16 h = f2bu(w);
    hi[e] = h;
    lo[e] = f2bu(w - bu2f(h));
  }
  if (mat == 2) {
    *(u16x8*)(wpv + ((size_t)(tt * 32 + kc) * 64 + lane) * 8) = hi;
  } else {
    u16* p = ((mat == 0) ? wpq : wpk) +
             (((size_t)(tt * 32 + kc) * 2 + 0) * 64 + lane) * 8;
    *(u16x8*)p         = hi;
    *(u16x8*)(p + 512) = lo;
  }
}

// ---------------------------------------------------------------------------
// Kernel 1: projections v6.
//  - BM=128, 4 waves, each wave owns 2 m-subtiles (rows 32w+16s) -> every
//    W fragment read from LDS feeds TWO MFMAs (halves LDS-read bytes/MFMA).
//  - x is NEVER staged: per-lane direct global fragment loads (16 rows x
//    64B lines fully consumed across lg lanes = coalesced-equivalent),
//    L2-resident since all 1024 blocks are co-resident.
//  - 8 n-groups (1 q + 1 k + 1 v tile each); W slice double-buffered in
//    LDS (20 KB total) -> 4 blocks/CU. Single barrier per K-step.
//  - bid = ng*128 + mt (128%8==0: x-sharers land on same XCD).
// ---------------------------------------------------------------------------
__global__ __launch_bounds__(256, 4) void proj_kernel(
    const float* __restrict__ x,
    const u16* __restrict__ wpq, const u16* __restrict__ wpk,
    const u16* __restrict__ wpv,
    u16* __restrict__ qpk, u16* __restrict__ kpk, u16* __restrict__ vpk) {
  __shared__ u16 wsl[2][1280 * 8];         // 20 KB: [kcg2][plane5][lane64][e8] x2
  const int tid  = threadIdx.x;
  const int ng   = blockIdx.x >> 7;        // 0..7
  const int mt   = blockIdx.x & 127;       // 0..127
  const int m0   = mt * 128;
  const int w    = tid >> 6;               // 0..3
  const int lane = tid & 63;
  const int lg   = lane >> 4, lc = lane & 15;

  // hoisted W staging source (ks-invariant). 5 rounds of 256 threads cover
  // 2 kcg x 5 planes x 64 lanes. planes: 0,1=q hi/lo; 2,3=k hi/lo; 4=v.
  const u16* wbase[5];
  int wstep[5];
  #pragma unroll
  for (int i = 0; i < 5; ++i) {
    const int c = tid + 256 * i;           // 0..1279
    const int kcg   = c >= 640;
    const int rem   = c - kcg * 640;
    const int plane = rem >> 6;
    const int ln    = rem & 63;
    const u16* base;
    int stride;
    if (plane < 2) {
      base = wpq + (size_t)(ng * 32) * 1024 + plane * 512 + ln * 8;
      stride = 1024;
    } else if (plane < 4) {
      base = wpk + (size_t)(ng * 32) * 1024 + (plane - 2) * 512 + ln * 8;
      stride = 1024;
    } else {
      base = wpv + (size_t)(ng * 32) * 512 + ln * 8;
      stride = 512;
    }
    wbase[i] = base + kcg * stride;
    wstep[i] = 2 * stride;
  }

  // hoisted x fragment sources for the 2 m-subtiles
  const float* xs0 = x + (size_t)(m0 + 32 * w + lc) * C + 4 * lg;
  const float* xs1 = xs0 + 16 * C;

  f32x4 zero = {0.f, 0.f, 0.f, 0.f};
  f32x4 accq[2], acck[2], accv[2];
  #pragma unroll
  for (int s = 0; s < 2; ++s) { accq[s] = zero; acck[s] = zero; accv[s] = zero; }

  u16x8 wreg[5];
  auto loadW = [&](int ks) {
    const int k = ks > 15 ? 15 : ks;
    #pragma unroll
    for (int i = 0; i < 5; ++i)
      wreg[i] = *(const u16x8*)(wbase[i] + (size_t)k * wstep[i]);
  };
  auto writeW = [&](int buf) {
    #pragma unroll
    for (int i = 0; i < 5; ++i)
      *(u16x8*)&wsl[buf][(size_t)(tid + 256 * i) * 8] = wreg[i];
  };

  auto compute = [&](int buf, int ks) {
    f32x4 xr0[4], xr1[4];
    #pragma unroll
    for (int j = 0; j < 4; ++j) {
      xr0[j] = *(const f32x4*)(xs0 + ks * 64 + 16 * j);
      xr1[j] = *(const f32x4*)(xs1 + ks * 64 + 16 * j);
    }
    #pragma unroll
    for (int kc = 0; kc < 2; ++kc) {
      Frag axh0, axl0, axh1, axl1;
      #pragma unroll
      for (int e = 0; e < 4; ++e) {
        u16 h;
        h = f2bu(xr0[2 * kc][e]);     axh0.s[e] = h;     axl0.s[e] = f2bu(xr0[2 * kc][e] - bu2f(h));
        h = f2bu(xr0[2 * kc + 1][e]); axh0.s[e + 4] = h; axl0.s[e + 4] = f2bu(xr0[2 * kc + 1][e] - bu2f(h));
        h = f2bu(xr1[2 * kc][e]);     axh1.s[e] = h;     axl1.s[e] = f2bu(xr1[2 * kc][e] - bu2f(h));
        h = f2bu(xr1[2 * kc + 1][e]); axh1.s[e + 4] = h; axl1.s[e + 4] = f2bu(xr1[2 * kc + 1][e] - bu2f(h));
      }
      const u16* wb = &wsl[buf][(size_t)(kc * 640) * 8];
      Frag qh, ql, kh, kl, vh;
      qh.u4 = *(const u32x4*)(wb + ((size_t)(0 * 64) + lane) * 8);
      ql.u4 = *(const u32x4*)(wb + ((size_t)(1 * 64) + lane) * 8);
      kh.u4 = *(const u32x4*)(wb + ((size_t)(2 * 64) + lane) * 8);
      kl.u4 = *(const u32x4*)(wb + ((size_t)(3 * 64) + lane) * 8);
      vh.u4 = *(const u32x4*)(wb + ((size_t)(4 * 64) + lane) * 8);
      // interleave the two independent m-subtile chains
      accq[0] = MFMA(axh0.v, qh.v, accq[0]);  accq[1] = MFMA(axh1.v, qh.v, accq[1]);
      accq[0] = MFMA(axh0.v, ql.v, accq[0]);  accq[1] = MFMA(axh1.v, ql.v, accq[1]);
      accq[0] = MFMA(axl0.v, qh.v, accq[0]);  accq[1] = MFMA(axl1.v, qh.v, accq[1]);
      acck[0] = MFMA(axh0.v, kh.v, acck[0]);  acck[1] = MFMA(axh1.v, kh.v, acck[1]);
      acck[0] = MFMA(axh0.v, kl.v, acck[0]);  acck[1] = MFMA(axh1.v, kl.v, acck[1]);
      acck[0] = MFMA(axl0.v, kh.v, acck[0]);  acck[1] = MFMA(axl1.v, kh.v, acck[1]);
      accv[0] = MFMA(axh0.v, vh.v, accv[0]);  accv[1] = MFMA(axh1.v, vh.v, accv[1]);
    }
  };

  // prologue: wsl[0] = W(0); wreg = W(1)
  loadW(0);
  writeW(0);
  loadW(1);
  __syncthreads();
  int cur = 0;
  for (int ks = 0; ks < 16; ++ks) {
    writeW(cur ^ 1);                 // wsl[nxt] = W(ks+1)   (safe: all waves
                                     // finished reading it last step, pre-barrier)
    loadW(ks + 2);                   // wreg = W(ks+2) (clamped; in flight under compute)
    compute(cur, ks);                // x global loads + 28 MFMA from wsl[cur]
    __syncthreads();                 // single barrier per K-step
    cur ^= 1;
  }

  // Epilogue: value = Out[m0 + 32w + 16s + 4lg + r][ng*16 + lc]
  #pragma unroll
  for (int s = 0; s < 2; ++s) {
    const int tb_abs = mt * 8 + 2 * w + s;
    const int b  = tb_abs >> 7;
    const int tb = tb_abs & 127;
    const int hs = ng >> 1;
    const int eq = (lc & 3) + 4 * (ng & 1);
    const int lane_cq = 4 * lg + 16 * (lc >> 2);
    #pragma unroll
    for (int r = 0; r < 4; ++r) {
      // q
      {
        const float val = accq[s][r];
        const u16 hvv = f2bu(val);
        u16* dst = qpk + (((size_t)(b * 128 + tb) * 4 + hs) * 2 * 64 + lane_cq + r) * 8 + eq;
        dst[0]   = hvv;
        dst[512] = f2bu(val - bu2f(hvv));
      }
      // k
      {
        const float val = acck[s][r];
        const u16 hvv = f2bu(val);
        u16* dst = kpk + (((size_t)(b * 128 + tb) * 4 + hs) * 2 * 64 + lane_cq + r) * 8 + eq;
        dst[0]   = hvv;
        dst[512] = f2bu(val - bu2f(hvv));
      }
      // v
      {
        const int kt = tb >> 1;
        const int lane_c = lc + 16 * lg;
        const int e = r + 4 * (tb & 1);
        vpk[(((size_t)(b * 64 + kt) * 8 + ng) * 64 + lane_c) * 8 + e] = f2bu(accv[s][r]);
      }
    }
  }
}

// ---------------------------------------------------------------------------
// Kernel 2: causal flash attention (round-4 structure + setprio on MFMA
// clusters). 8 waves, intra-block split-K (kb = w mod 8), 1 q-tile/wave.
// Swapped QK^T so P lands in PV's A-operand layout. LDS combine (bf16).
// ---------------------------------------------------------------------------
__global__ __launch_bounds__(512, 4) void attn_kernel(
    const u16* __restrict__ qpk, const u16* __restrict__ kpk,
    const u16* __restrict__ vpk, float* __restrict__ out) {
  __shared__ float lm[8][16];
  __shared__ float ll[8][16];
  __shared__ u16 lo[8][16][132];     // bf16 partial O

  const int bid = blockIdx.x;
  const int b   = bid & 7;           // batch -> XCD affinity
  const int qt  = bid >> 3;          // 0..127
  const int w    = threadIdx.x >> 6;
  const int lane = threadIdx.x & 63;
  const int lg = lane >> 4, lc = lane & 15;

  // Q fragments: [b][qt][hs][hl][lane][8], tile stride 4096 u16
  Frag bqh[4], bql[4];
  const u16* qp = qpk + (size_t)(b * 128 + qt) * 4096 + lane * 8;
  #pragma unroll
  for (int hs = 0; hs < 4; ++hs) {
    bqh[hs].u4 = *(const u32x4*)(qp + (size_t)(hs * 2 + 0) * 512);
    bql[hs].u4 = *(const u32x4*)(qp + (size_t)(hs * 2 + 1) * 512);
  }

  f32x4 zero = {0.f, 0.f, 0.f, 0.f};
  f32x4 o_acc[8];
  #pragma unroll
  for (int i = 0; i < 8; ++i) o_acc[i] = zero;
  float m_run = -INFINITY, l_run = 0.f;

  const int myq = qt * 16 + lc;
  const int nkb = qt >> 2;           // last 64-wide k-block

  for (int kb = w; kb <= nkb; kb += 8) {
    f32x4 s[4];
    #pragma unroll
    for (int t = 0; t < 4; ++t) s[t] = zero;

    const u16* kp = kpk + (size_t)(b * 128 + kb * 4) * 4096 + lane * 8;
    __builtin_amdgcn_s_setprio(1);
    #pragma unroll
    for (int t = 0; t < 4; ++t) {
      #pragma unroll
      for (int hs = 0; hs < 4; ++hs) {
        const u16* p = kp + (size_t)(t * 8 + hs * 2) * 512;
        Frag akh, akl;
        akh.u4 = *(const u32x4*)p;
        akl.u4 = *(const u32x4*)(p + 512);
        s[t] = MFMA(akh.v, bqh[hs].v, s[t]);
        s[t] = MFMA(akh.v, bql[hs].v, s[t]);
        s[t] = MFMA(akl.v, bqh[hs].v, s[t]);
      }
    }
    __builtin_amdgcn_s_setprio(0);

    // scale by sqrt(C)=32; causal + (tril==0 -> -inf) semantics
    float pmax = -INFINITY;
    #pragma unroll
    for (int t = 0; t < 4; ++t) {
      #pragma unroll
      for (int r = 0; r < 4; ++r) {
        const int kk = kb * 64 + t * 16 + 4 * lg + r;
        float v = s[t][r] * 32.0f;
        if (kk > myq || v == 0.0f) v = -INFINITY;
        s[t][r] = v;
        pmax = fmaxf(pmax, v);
      }
    }
    pmax = fmaxf(pmax, __shfl_xor(pmax, 16));
    pmax = fmaxf(pmax, __shfl_xor(pmax, 32));
    const float m_new = fmaxf(m_run, pmax);
    const float alpha = __expf(m_run - m_new);

    float sum = 0.f;
    u16 pb[16];
    #pragma unroll
    for (int t = 0; t < 4; ++t) {
      #pragma unroll
      for (int r = 0; r < 4; ++r) {
        const float p = __expf(s[t][r] - m_new);
        sum += p;
        pb[t * 4 + r] = f2bu(p);
      }
    }
    sum += __shfl_xor(sum, 16);
    sum += __shfl_xor(sum, 32);
    l_run = l_run * alpha + sum;
    m_run = m_new;

    float al[4];
    #pragma unroll
    for (int r = 0; r < 4; ++r) al[r] = __shfl(alpha, 4 * lg + r);
    #pragma unroll
    for (int i = 0; i < 8; ++i) {
      #pragma unroll
      for (int r = 0; r < 4; ++r) o_acc[i][r] *= al[r];
    }

    Frag pa[2];
    #pragma unroll
    for (int ks = 0; ks < 2; ++ks) {
      #pragma unroll
      for (int e = 0; e < 8; ++e)
        pa[ks].s[e] = pb[(2 * ks + (e >> 2)) * 4 + (e & 3)];
    }

    __builtin_amdgcn_s_setprio(1);
    #pragma unroll
    for (int ks = 0; ks < 2; ++ks) {
      const u16* vp = vpk + (size_t)(b * 64 + kb * 2 + ks) * 4096 + lane * 8;
      #pragma unroll
      for (int ht = 0; ht < 8; ++ht) {
        Frag bv;
        bv.u4 = *(const u32x4*)(vp + (size_t)ht * 512);
        o_acc[ht] = MFMA(pa[ks].v, bv.v, o_acc[ht]);
      }
    }
    __builtin_amdgcn_s_setprio(0);
  }

  // --- combine 8 partials through LDS ---
  if (lane < 16) { lm[w][lane] = m_run; ll[w][lane] = l_run; }
  #pragma unroll
  for (int ht = 0; ht < 8; ++ht)
    #pragma unroll
    for (int r = 0; r < 4; ++r)
      lo[w][4 * lg + r][ht * 16 + lc] = f2bu(o_acc[ht][r]);
  __syncthreads();

  const int tid = threadIdx.x;
  const int q  = tid >> 5;            // 0..15
  const int hb = (tid & 31) * 4;      // 0..124
  float M = -INFINITY;
  #pragma unroll
  for (int ww = 0; ww < 8; ++ww) M = fmaxf(M, lm[ww][q]);
  float lsum = 0.f;
  f32x4 osum = {0.f, 0.f, 0.f, 0.f};
  #pragma unroll
  for (int ww = 0; ww < 8; ++ww) {
    const float sc = __expf(lm[ww][q] - M);
    lsum += sc * ll[ww][q];
    const u16x4 ov = *(const u16x4*)&lo[ww][q][hb];
    #pragma unroll
    for (int j = 0; j < 4; ++j) osum[j] += sc * bu2f(ov[j]);
  }
  const float inv = 1.0f / lsum;
  f32x4 res = {osum[0] * inv, osum[1] * inv, osum[2] * inv, osum[3] * inv};
  *(f32x4*)&out[((size_t)(b * T + qt * 16 + q)) * H + hb] = res;
}

// ---------------------------------------------------------------------------
extern "C" void kernel_launch(void* const* d_in, const int* in_sizes, int n_in,
                              void* d_out, int out_size, void* d_ws, size_t ws_size,
                              hipStream_t stream) {
  (void)in_sizes; (void)n_in; (void)out_size; (void)ws_size;
  const float* x  = (const float*)d_in[0];
  const float* Wk = (const float*)d_in[1];
  const float* Wq = (const float*)d_in[2];
  const float* Wv = (const float*)d_in[3];
  float* out = (float*)d_out;

  u16* w = (u16*)d_ws;
  const size_t WPQK = (size_t)8 * 32 * 2 * 64 * 8;       // 262144
  const size_t WPV  = (size_t)8 * 32 * 64 * 8;           // 131072
  const size_t QKP  = (size_t)NB * 128 * 4 * 2 * 64 * 8; // 4194304
  u16* wpq = w;
  u16* wpk = wpq + WPQK;
  u16* wpv = wpk + WPQK;
  u16* qpk = wpv + WPV;
  u16* kpk = qpk + QKP;
  u16* vpk = kpk + QKP;

  prep_w<<<192, 256, 0, stream>>>(Wk, Wq, Wv, wpq, wpk, wpv);
  proj_kernel<<<1024, 256, 0, stream>>>(x, wpq, wpk, wpv, qpk, kpk, vpk);
  attn_kernel<<<NB * (T / 16), 512, 0, stream>>>(qpk, kpk, vpk, out);
}

// Round 11
// 97.745 us; speedup vs baseline: 1.3648x; 1.3648x over previous
//
#include <hip/hip_runtime.h>
#include <hip/hip_bf16.h>

typedef float  f32x4  __attribute__((ext_vector_type(4)));
typedef __bf16 bf16x8 __attribute__((ext_vector_type(8)));
typedef unsigned int   u32;
typedef unsigned short u16;
typedef u32   u32x2  __attribute__((ext_vector_type(2)));
typedef u32   u32x4  __attribute__((ext_vector_type(4)));
typedef u16   u16x4  __attribute__((ext_vector_type(4)));
typedef u16   u16x8  __attribute__((ext_vector_type(8)));

#define DEV __device__ __forceinline__

constexpr int NB = 8, T = 2048, C = 1024, H = 128;
constexpr int BT = NB * T;

union Frag {
  bf16x8 v;
  u32x4  u4;
  u32x2  u2[2];
  u32    u[4];
  u16    s[8];
};

DEV u16 f2bu(float f) {
  __hip_bfloat16 h = __float2bfloat16(f);
  return __builtin_bit_cast(u16, h);
}
DEV float bu2f(u16 u) {
  return __bfloat162float(__builtin_bit_cast(__hip_bfloat16, u));
}
DEV f32x4 MFMA(bf16x8 a, bf16x8 b, f32x4 c) {
  return __builtin_amdgcn_mfma_f32_16x16x32_bf16(a, b, c, 0, 0, 0);
}

// ---------------------------------------------------------------------------
// Lane-contiguous fragment layouts (16B/lane, 1KB/wave per load):
//   wpq/wpk: [tt8][kc32][hl2][lane64][e8]        (tile-kc stride 1024 u16)
//   wpv:     [tt8][kc32][lane64][e8]             (512)
//   qpk/kpk: [b8][tile128][hs4][hl2][lane64][e8] (tile stride 4096)
//   vpk:     [b8][kt64][ht8][lane64][e8]         (kt stride 4096)
// ---------------------------------------------------------------------------

__global__ void prep_w(const float* __restrict__ Wk, const float* __restrict__ Wq,
                       const float* __restrict__ Wv,
                       u16* __restrict__ wpq, u16* __restrict__ wpk,
                       u16* __restrict__ wpv) {
  const int id = blockIdx.x * 256 + threadIdx.x;   // 24*32*64 = 49152
  if (id >= 24 * 32 * 64) return;
  const int lane = id & 63;
  const int kc   = (id >> 6) & 31;
  const int tile = id >> 11;          // 0..23
  const int mat  = tile >> 3;         // 0=q 1=k 2=v
  const int tt   = tile & 7;
  const int n    = tt * 16 + (lane & 15);
  const float* W = (mat == 0) ? Wq : (mat == 1) ? Wk : Wv;
  u16x8 hi, lo;
  #pragma unroll
  for (int e = 0; e < 8; ++e) {
    const int k = kc * 32 + 4 * (lane >> 4) + (e & 3) + 16 * (e >> 2);
    const float w = W[(size_t)k * H + n];
    u16 h = f2bu(w);
    hi[e] = h;
    lo[e] = f2bu(w - bu2f(h));
  }
  if (mat == 2) {
    *(u16x8*)(wpv + ((size_t)(tt * 32 + kc) * 64 + lane) * 8) = hi;
  } else {
    u16* p = ((mat == 0) ? wpq : wpk) +
             (((size_t)(tt * 32 + kc) * 2 + 0) * 64 + lane) * 8;
    *(u16x8*)p         = hi;
    *(u16x8*)(p + 512) = lo;
  }
}

// ---------------------------------------------------------------------------
// Kernel 1: projections v7 = r7 tile structure + full double-buffer single-
// barrier pipeline at BK=32.
//  - BM=128, 4 waves, wave owns 2 m-subtiles (rows 32w+16s) x 6 n-tiles
//    (2q+2k+2v of n-group ng) -> 512B LDS-read per MFMA.
//  - x AND W double-buffered in LDS (57 KB total -> 2 blocks/CU); global
//    loads for step ks+2 issued during step ks; writes go to the idle
//    buffer before the single per-step barrier (r9-proven pattern).
//  - x loads: 8 lanes/row, 16 fully-consumed 64B lines per instruction.
//  - bid = ng*128 + mt (128%8==0: x-sharers land on same XCD).
// ---------------------------------------------------------------------------
__global__ __launch_bounds__(256, 2) void proj_kernel(
    const float* __restrict__ x,
    const u16* __restrict__ wpq, const u16* __restrict__ wpk,
    const u16* __restrict__ wpv,
    u16* __restrict__ qpk, u16* __restrict__ kpk, u16* __restrict__ vpk) {
  __shared__ u16 xh[2][128][36];       // 18.4 KB
  __shared__ u16 xl[2][128][36];       // 18.4 KB
  __shared__ u16 wsl[2][640 * 8];      // 20.5 KB: [plane10][lane64][e8]
  const int tid  = threadIdx.x;
  const int ng   = blockIdx.x >> 7;        // 0..3
  const int mt   = blockIdx.x & 127;       // 0..127
  const int m0   = mt * 128;
  const int w    = tid >> 6;               // 0..3
  const int lane = tid & 63;
  const int lg   = lane >> 4, lc = lane & 15;

  // ---- hoisted W staging coords: 640 chunks = 10 planes x 64 lanes;
  // planes: 0-3 q(jt,hl), 4-7 k(jt,hl), 8-9 v(jt).
  const u16* wbase[3];
  int wstep[3], wofs[3];
  bool wact[3];
  #pragma unroll
  for (int i = 0; i < 3; ++i) {
    const int c = tid + 256 * i;
    wact[i] = (c < 640);
    const int cc = wact[i] ? c : 0;
    const int p  = cc >> 6;
    const int ln = cc & 63;
    const u16* base;
    int stride;
    if (p < 4) {
      base = wpq + (size_t)((2 * ng + (p >> 1)) * 32) * 1024 + (p & 1) * 512 + ln * 8;
      stride = 1024;
    } else if (p < 8) {
      base = wpk + (size_t)((2 * ng + ((p - 4) >> 1)) * 32) * 1024 + ((p - 4) & 1) * 512 + ln * 8;
      stride = 1024;
    } else {
      base = wpv + (size_t)((2 * ng + (p - 8)) * 32) * 512 + ln * 8;
      stride = 512;
    }
    wbase[i] = base;
    wstep[i] = stride;
    wofs[i]  = (p * 64 + ln) * 8;
  }

  f32x4 zero = {0.f, 0.f, 0.f, 0.f};
  f32x4 acc[6][2];                         // [j=mat*2+jt][msub]
  #pragma unroll
  for (int j = 0; j < 6; ++j)
    #pragma unroll
    for (int s = 0; s < 2; ++s) acc[j][s] = zero;

  f32x4 xreg[4];
  u16x8 wreg[3];

  auto loadX = [&](int ks) {
    const int k = ks > 31 ? 31 : ks;
    #pragma unroll
    for (int j = 0; j < 4; ++j) {
      const int idx = tid + 256 * j;       // 0..1023
      const int row = idx >> 3;
      const int c4  = (idx & 7) * 4;
      xreg[j] = *(const f32x4*)&x[(size_t)(m0 + row) * C + k * 32 + c4];
    }
  };
  auto writeX = [&](int buf) {
    #pragma unroll
    for (int j = 0; j < 4; ++j) {
      const int idx = tid + 256 * j;
      const int row = idx >> 3;
      const int c4  = (idx & 7) * 4;
      u16x4 hv, lv;
      #pragma unroll
      for (int e = 0; e < 4; ++e) {
        u16 h = f2bu(xreg[j][e]);
        hv[e] = h;
        lv[e] = f2bu(xreg[j][e] - bu2f(h));
      }
      *(u16x4*)&xh[buf][row][c4] = hv;
      *(u16x4*)&xl[buf][row][c4] = lv;
    }
  };
  auto loadW = [&](int ks) {
    const int k = ks > 31 ? 31 : ks;
    #pragma unroll
    for (int i = 0; i < 3; ++i)
      if (wact[i]) wreg[i] = *(const u16x8*)(wbase[i] + (size_t)k * wstep[i]);
  };
  auto writeW = [&](int buf) {
    #pragma unroll
    for (int i = 0; i < 3; ++i)
      if (wact[i]) *(u16x8*)&wsl[buf][wofs[i]] = wreg[i];
  };

  auto compute = [&](int buf) {
    Frag axh[2], axl[2];
    #pragma unroll
    for (int s = 0; s < 2; ++s) {
      const int row = 32 * w + 16 * s + lc;
      axh[s].u2[0] = *(const u32x2*)&xh[buf][row][4 * lg];
      axh[s].u2[1] = *(const u32x2*)&xh[buf][row][16 + 4 * lg];
      axl[s].u2[0] = *(const u32x2*)&xl[buf][row][4 * lg];
      axl[s].u2[1] = *(const u32x2*)&xl[buf][row][16 + 4 * lg];
    }
    #pragma unroll
    for (int jt = 0; jt < 2; ++jt) {
      Frag qh, ql, kh, kl, vh;
      qh.u4 = *(const u32x4*)&wsl[buf][((0 + jt * 2 + 0) * 64 + lane) * 8];
      ql.u4 = *(const u32x4*)&wsl[buf][((0 + jt * 2 + 1) * 64 + lane) * 8];
      kh.u4 = *(const u32x4*)&wsl[buf][((4 + jt * 2 + 0) * 64 + lane) * 8];
      kl.u4 = *(const u32x4*)&wsl[buf][((4 + jt * 2 + 1) * 64 + lane) * 8];
      vh.u4 = *(const u32x4*)&wsl[buf][((8 + jt) * 64 + lane) * 8];
      #pragma unroll
      for (int s = 0; s < 2; ++s) {
        acc[jt][s]     = MFMA(axh[s].v, qh.v, acc[jt][s]);
        acc[jt][s]     = MFMA(axh[s].v, ql.v, acc[jt][s]);
        acc[jt][s]     = MFMA(axl[s].v, qh.v, acc[jt][s]);
        acc[2 + jt][s] = MFMA(axh[s].v, kh.v, acc[2 + jt][s]);
        acc[2 + jt][s] = MFMA(axh[s].v, kl.v, acc[2 + jt][s]);
        acc[2 + jt][s] = MFMA(axl[s].v, kh.v, acc[2 + jt][s]);
        acc[4 + jt][s] = MFMA(axh[s].v, vh.v, acc[4 + jt][s]);
      }
    }
  };

  // prologue: buf0 = step 0; regs = step 1
  loadX(0); loadW(0);
  writeX(0); writeW(0);
  loadX(1); loadW(1);
  __syncthreads();
  int cur = 0;
  for (int ks = 0; ks < 32; ++ks) {
    writeX(cur ^ 1);                 // regs hold step ks+1; idle buffer (its
    writeW(cur ^ 1);                 //  readers finished before last barrier)
    loadX(ks + 2);                   // issue step-(ks+2) loads under compute
    loadW(ks + 2);
    compute(cur);                    // 28 MFMA from buf[cur]
    __syncthreads();                 // single barrier per K-step
    cur ^= 1;
  }

  // Epilogue (r7-verified): value = Out[m0 + 32w + 16s + 4lg + r][(2ng+jt)*16 + lc]
  #pragma unroll
  for (int s = 0; s < 2; ++s) {
    const int tb_abs = mt * 8 + 2 * w + s;
    const int b  = tb_abs >> 7;
    const int tb = tb_abs & 127;
    #pragma unroll
    for (int j = 0; j < 6; ++j) {
      const int mat = j >> 1;
      const int jt  = j & 1;
      const int tt  = 2 * ng + jt;
      #pragma unroll
      for (int r = 0; r < 4; ++r) {
        const float val = acc[j][s][r];
        if (mat < 2) {
          const u16 hvv = f2bu(val);
          const u16 lvv = f2bu(val - bu2f(hvv));
          const int lane_c = 4 * lg + r + 16 * (lc >> 2);
          const int hs = tt >> 1;
          const int e  = (lc & 3) + 4 * (tt & 1);
          u16* dst = ((mat == 0) ? qpk : kpk) +
                     (((size_t)(b * 128 + tb) * 4 + hs) * 2 * 64 + lane_c) * 8 + e;
          dst[0]   = hvv;
          dst[512] = lvv;
        } else {
          const int kt = tb >> 1;
          const int lane_c = lc + 16 * lg;
          const int e = r + 4 * (tb & 1);
          vpk[(((size_t)(b * 64 + kt) * 8 + tt) * 64 + lane_c) * 8 + e] = f2bu(val);
        }
      }
    }
  }
}

// ---------------------------------------------------------------------------
// Kernel 2: causal flash attention (round-4 structure + setprio on MFMA
// clusters). 8 waves, intra-block split-K (kb = w mod 8), 1 q-tile/wave.
// Swapped QK^T so P lands in PV's A-operand layout. LDS combine (bf16).
// ---------------------------------------------------------------------------
__global__ __launch_bounds__(512, 4) void attn_kernel(
    const u16* __restrict__ qpk, const u16* __restrict__ kpk,
    const u16* __restrict__ vpk, float* __restrict__ out) {
  __shared__ float lm[8][16];
  __shared__ float ll[8][16];
  __shared__ u16 lo[8][16][132];     // bf16 partial O

  const int bid = blockIdx.x;
  const int b   = bid & 7;           // batch -> XCD affinity
  const int qt  = bid >> 3;          // 0..127
  const int w    = threadIdx.x >> 6;
  const int lane = threadIdx.x & 63;
  const int lg = lane >> 4, lc = lane & 15;

  // Q fragments: [b][qt][hs][hl][lane][8], tile stride 4096 u16
  Frag bqh[4], bql[4];
  const u16* qp = qpk + (size_t)(b * 128 + qt) * 4096 + lane * 8;
  #pragma unroll
  for (int hs = 0; hs < 4; ++hs) {
    bqh[hs].u4 = *(const u32x4*)(qp + (size_t)(hs * 2 + 0) * 512);
    bql[hs].u4 = *(const u32x4*)(qp + (size_t)(hs * 2 + 1) * 512);
  }

  f32x4 zero = {0.f, 0.f, 0.f, 0.f};
  f32x4 o_acc[8];
  #pragma unroll
  for (int i = 0; i < 8; ++i) o_acc[i] = zero;
  float m_run = -INFINITY, l_run = 0.f;

  const int myq = qt * 16 + lc;
  const int nkb = qt >> 2;           // last 64-wide k-block

  for (int kb = w; kb <= nkb; kb += 8) {
    f32x4 s[4];
    #pragma unroll
    for (int t = 0; t < 4; ++t) s[t] = zero;

    const u16* kp = kpk + (size_t)(b * 128 + kb * 4) * 4096 + lane * 8;
    __builtin_amdgcn_s_setprio(1);
    #pragma unroll
    for (int t = 0; t < 4; ++t) {
      #pragma unroll
      for (int hs = 0; hs < 4; ++hs) {
        const u16* p = kp + (size_t)(t * 8 + hs * 2) * 512;
        Frag akh, akl;
        akh.u4 = *(const u32x4*)p;
        akl.u4 = *(const u32x4*)(p + 512);
        s[t] = MFMA(akh.v, bqh[hs].v, s[t]);
        s[t] = MFMA(akh.v, bql[hs].v, s[t]);
        s[t] = MFMA(akl.v, bqh[hs].v, s[t]);
      }
    }
    __builtin_amdgcn_s_setprio(0);

    // scale by sqrt(C)=32; causal + (tril==0 -> -inf) semantics
    float pmax = -INFINITY;
    #pragma unroll
    for (int t = 0; t < 4; ++t) {
      #pragma unroll
      for (int r = 0; r < 4; ++r) {
        const int kk = kb * 64 + t * 16 + 4 * lg + r;
        float v = s[t][r] * 32.0f;
        if (kk > myq || v == 0.0f) v = -INFINITY;
        s[t][r] = v;
        pmax = fmaxf(pmax, v);
      }
    }
    pmax = fmaxf(pmax, __shfl_xor(pmax, 16));
    pmax = fmaxf(pmax, __shfl_xor(pmax, 32));
    const float m_new = fmaxf(m_run, pmax);
    const float alpha = __expf(m_run - m_new);

    float sum = 0.f;
    u16 pb[16];
    #pragma unroll
    for (int t = 0; t < 4; ++t) {
      #pragma unroll
      for (int r = 0; r < 4; ++r) {
        const float p = __expf(s[t][r] - m_new);
        sum += p;
        pb[t * 4 + r] = f2bu(p);
      }
    }
    sum += __shfl_xor(sum, 16);
    sum += __shfl_xor(sum, 32);
    l_run = l_run * alpha + sum;
    m_run = m_new;

    float al[4];
    #pragma unroll
    for (int r = 0; r < 4; ++r) al[r] = __shfl(alpha, 4 * lg + r);
    #pragma unroll
    for (int i = 0; i < 8; ++i) {
      #pragma unroll
      for (int r = 0; r < 4; ++r) o_acc[i][r] *= al[r];
    }

    Frag pa[2];
    #pragma unroll
    for (int ks = 0; ks < 2; ++ks) {
      #pragma unroll
      for (int e = 0; e < 8; ++e)
        pa[ks].s[e] = pb[(2 * ks + (e >> 2)) * 4 + (e & 3)];
    }

    __builtin_amdgcn_s_setprio(1);
    #pragma unroll
    for (int ks = 0; ks < 2; ++ks) {
      const u16* vp = vpk + (size_t)(b * 64 + kb * 2 + ks) * 4096 + lane * 8;
      #pragma unroll
      for (int ht = 0; ht < 8; ++ht) {
        Frag bv;
        bv.u4 = *(const u32x4*)(vp + (size_t)ht * 512);
        o_acc[ht] = MFMA(pa[ks].v, bv.v, o_acc[ht]);
      }
    }
    __builtin_amdgcn_s_setprio(0);
  }

  // --- combine 8 partials through LDS ---
  if (lane < 16) { lm[w][lane] = m_run; ll[w][lane] = l_run; }
  #pragma unroll
  for (int ht = 0; ht < 8; ++ht)
    #pragma unroll
    for (int r = 0; r < 4; ++r)
      lo[w][4 * lg + r][ht * 16 + lc] = f2bu(o_acc[ht][r]);
  __syncthreads();

  const int tid = threadIdx.x;
  const int q  = tid >> 5;            // 0..15
  const int hb = (tid & 31) * 4;      // 0..124
  float M = -INFINITY;
  #pragma unroll
  for (int ww = 0; ww < 8; ++ww) M = fmaxf(M, lm[ww][q]);
  float lsum = 0.f;
  f32x4 osum = {0.f, 0.f, 0.f, 0.f};
  #pragma unroll
  for (int ww = 0; ww < 8; ++ww) {
    const float sc = __expf(lm[ww][q] - M);
    lsum += sc * ll[ww][q];
    const u16x4 ov = *(const u16x4*)&lo[ww][q][hb];
    #pragma unroll
    for (int j = 0; j < 4; ++j) osum[j] += sc * bu2f(ov[j]);
  }
  const float inv = 1.0f / lsum;
  f32x4 res = {osum[0] * inv, osum[1] * inv, osum[2] * inv, osum[3] * inv};
  *(f32x4*)&out[((size_t)(b * T + qt * 16 + q)) * H + hb] = res;
}

// ---------------------------------------------------------------------------
extern "C" void kernel_launch(void* const* d_in, const int* in_sizes, int n_in,
                              void* d_out, int out_size, void* d_ws, size_t ws_size,
                              hipStream_t stream) {
  (void)in_sizes; (void)n_in; (void)out_size; (void)ws_size;
  const float* x  = (const float*)d_in[0];
  const float* Wk = (const float*)d_in[1];
  const float* Wq = (const float*)d_in[2];
  const float* Wv = (const float*)d_in[3];
  float* out = (float*)d_out;

  u16* w = (u16*)d_ws;
  const size_t WPQK = (size_t)8 * 32 * 2 * 64 * 8;       // 262144
  const size_t WPV  = (size_t)8 * 32 * 64 * 8;           // 131072
  const size_t QKP  = (size_t)NB * 128 * 4 * 2 * 64 * 8; // 4194304
  u16* wpq = w;
  u16* wpk = wpq + WPQK;
  u16* wpv = wpk + WPQK;
  u16* qpk = wpv + WPV;
  u16* kpk = qpk + QKP;
  u16* vpk = kpk + QKP;

  prep_w<<<192, 256, 0, stream>>>(Wk, Wq, Wv, wpq, wpk, wpv);
  proj_kernel<<<512, 256, 0, stream>>>(x, wpq, wpk, wpv, qpk, kpk, vpk);
  attn_kernel<<<NB * (T / 16), 512, 0, stream>>>(qpk, kpk, vpk, out);
}